// Round 19
// baseline (791.032 us; speedup 1.0000x reference)
//
#include <hip/hip_runtime.h>
#include <math.h>

#define NODES 50000
#define NEDGES 800000
#define ETOT (NEDGES + NODES)
#define FIN 16
#define PRE 32
#define C 128
#define GH 32
#define LAYERS 5
#define RECS 160   // f16 per node record: [B16perm:32 | hd16:128] where hd = dis[n]*h[n]
#define SCB 64     // scan blocks
#define SCT 256    // scan threads/block
#define SCCH ((NODES + SCB*SCT - 1) / (SCB*SCT))   // elems per thread (=4)
#define NB ((NODES + 255) >> 8)   // 196 coarse buckets (256 nodes each)
#define BCAP 6144                 // max real edges per bucket (mean 4096, +32 sigma)
#define LOUTC (BCAP + 256)        // LDS staging capacity (edges + self loops)
#define BIN_BLOCKS 98
#define EPB ((NEDGES + BIN_BLOCKS - 1) / BIN_BLOCKS)

typedef _Float16 f16;
typedef f16 f16x8 __attribute__((ext_vector_type(8)));
typedef f16 f16x4 __attribute__((ext_vector_type(4)));
typedef f16 f16x2 __attribute__((ext_vector_type(2)));
typedef float f32x4 __attribute__((ext_vector_type(4)));

__device__ __forceinline__ float sigmoidf_(float x) { return 1.0f / (1.0f + __expf(-x)); }

// XOR-swizzled LDS byte offset: 16B-block index ^= (row&7)  (stride >= 128B)
__device__ __forceinline__ int swz_off(int row, int bytecol, int stride) {
    return row * stride + ((((bytecol) >> 4) ^ (row & 7)) << 4) + (bytecol & 15);
}
// 64B-stride variant: block index ^= (row&3)
__device__ __forceinline__ int ps_off(int row, int bytecol) {
    return row * 64 + ((((bytecol) >> 4) ^ (row & 3)) << 4) + (bytecol & 15);
}

// gate channel c (0..31) -> permuted position, so msg lane k8 reads one vector
__device__ __forceinline__ int bperm(int c) { return 4 * (c & 7) + (c >> 3); }

__global__ void k_degree(const int* __restrict__ col, float* __restrict__ deg) {
    int e = blockIdx.x * blockDim.x + threadIdx.x;
    if (e < NEDGES) atomicAdd(&deg[col[e]], 1.0f);
}

// parallel scan, stage 1: per-block sums of (deg+1)
__global__ __launch_bounds__(SCT) void k_scan1(const float* __restrict__ deg, int* __restrict__ bsum) {
    __shared__ int ws4[SCT / 64];
    int b = blockIdx.x, t = threadIdx.x;
    int lane = t & 63, wv = t >> 6;
    int base = (b * SCT + t) * SCCH;
    int sum = 0;
#pragma unroll
    for (int j = 0; j < SCCH; j++) {
        int i = base + j;
        if (i < NODES) sum += (int)deg[i] + 1;
    }
#pragma unroll
    for (int off = 32; off > 0; off >>= 1) sum += __shfl_xor(sum, off, 64);
    if (lane == 0) ws4[wv] = sum;
    __syncthreads();
    if (t == 0) {
        int tot = 0;
#pragma unroll
        for (int j = 0; j < SCT / 64; j++) tot += ws4[j];
        bsum[b] = tot;
    }
}

// stage 2: exclusive scan of SCB block sums (single wave)
__global__ __launch_bounds__(64) void k_scan2(const int* __restrict__ bsum, int* __restrict__ bscan,
                                              int* __restrict__ start) {
    int t = threadIdx.x;
    int v = (t < SCB) ? bsum[t] : 0;
    int x = v;
#pragma unroll
    for (int off = 1; off < 64; off <<= 1) {
        int tt = __shfl_up(x, off, 64);
        if (t >= off) x += tt;
    }
    if (t < SCB) bscan[t] = x - v;
    if (t == SCB - 1) start[NODES] = x;
}

// stage 3: per-element exclusive prefix -> start; dis=rsqrt(deg+1), rdis=sqrt(deg+1)
__global__ __launch_bounds__(SCT) void k_scan3(
    float* __restrict__ deg_dis, float* __restrict__ rdis, const int* __restrict__ bscan,
    int* __restrict__ start) {
    __shared__ int woff[SCT / 64];
    int b = blockIdx.x, t = threadIdx.x;
    int lane = t & 63, wv = t >> 6;
    int base = (b * SCT + t) * SCCH;
    int v[SCCH]; int sum = 0;
#pragma unroll
    for (int j = 0; j < SCCH; j++) {
        int i = base + j;
        v[j] = (i < NODES) ? (int)deg_dis[i] + 1 : 0;
        sum += v[j];
    }
    int x = sum;
#pragma unroll
    for (int off = 1; off < 64; off <<= 1) {
        int tt = __shfl_up(x, off, 64);
        if (lane >= off) x += tt;
    }
    int texcl = x - sum;
    if (lane == 63) woff[wv] = x;
    __syncthreads();
    int wbase = 0;
    for (int j = 0; j < wv; j++) wbase += woff[j];
    int run = bscan[b] + wbase + texcl;
#pragma unroll
    for (int j = 0; j < SCCH; j++) {
        int i = base + j;
        if (i < NODES) {
            start[i] = run;
            float fv = (float)v[j];
            deg_dis[i] = rsqrtf(fv);
            rdis[i] = sqrtf(fv);
        }
        run += v[j];
    }
}

// CSR phase 1: hierarchical binning. Per block: LDS count -> one global reservation
// per bucket (padded counters) -> scatter into reserved contiguous chunk.
__global__ __launch_bounds__(256) void k_bucket2(
    const int* __restrict__ eidx, const float* __restrict__ eattr,
    int* __restrict__ bcnt /* NB, stride 16 ints */, int2* __restrict__ bbuf) {
    __shared__ int cnt[NB];
    __shared__ int gbase[NB];
    __shared__ int cur[NB];
    int b = blockIdx.x, t = threadIdx.x;
    int e0 = b * EPB;
    int e1 = e0 + EPB; if (e1 > NEDGES) e1 = NEDGES;
    for (int i = t; i < NB; i += 256) cnt[i] = 0;
    __syncthreads();
    for (int e = e0 + t; e < e1; e += 256) {
        int ci = eidx[NEDGES + e];
        atomicAdd(&cnt[ci >> 8], 1);
    }
    __syncthreads();
    for (int i = t; i < NB; i += 256) {
        gbase[i] = (cnt[i] > 0) ? atomicAdd(&bcnt[i * 16], cnt[i]) : 0;
        cur[i] = 0;
    }
    __syncthreads();
    for (int e = e0 + t; e < e1; e += 256) {
        int r = eidx[e], ci = eidx[NEDGES + e];
        float ea = eattr[e];
        int bk = ci >> 8;
        int pos = gbase[bk] + atomicAdd(&cur[bk], 1);
        if (pos < BCAP)
            bbuf[(size_t)bk * BCAP + pos] =
                make_int2((r & 0xFFFF) | ((ci & 255) << 16), __float_as_int(ea));
    }
}

// CSR phase 2: block per bucket; LDS-staged per-node grouping, dense contiguous flush
__global__ __launch_bounds__(256) void k_csr2(
    const int* __restrict__ bcnt, const int2* __restrict__ bbuf,
    const int* __restrict__ start, int2* __restrict__ esort) {
    __shared__ int2 lout[LOUTC];
    __shared__ int lcur[256];
    int b = blockIdx.x, t = threadIdx.x;
    int lo = b << 8;
    int hi = lo + 256; if (hi > NODES) hi = NODES;
    int nn = hi - lo;
    int sbase = start[lo];
    int total = start[hi] - sbase;
    if (t < nn) lcur[t] = start[lo + t] - sbase;
    __syncthreads();
    int n = bcnt[b * 16]; if (n > BCAP) n = BCAP;
    for (int i = t; i < n; i += 256) {
        int2 w = bbuf[(size_t)b * BCAP + i];
        int cil = (w.x >> 16) & 255;
        int r = w.x & 0xFFFF;
        int pos = atomicAdd(&lcur[cil], 1);
        if (pos < LOUTC) lout[pos] = make_int2(r, w.y);
    }
    if (t < nn) {   // self loop for each node
        int pos = atomicAdd(&lcur[t], 1);
        if (pos < LOUTC) lout[pos] = make_int2(lo + t, 0);
    }
    __syncthreads();
    int lim = total < LOUTC ? total : LOUTC;
    for (int i = t; i < lim; i += 256) esort[sbase + i] = lout[i];
}

// fragment-ordered f16 weight buffers.
__global__ __launch_bounds__(256) void k_prep_w(
    const float* __restrict__ Wz, const float* __restrict__ Wr, const float* __restrict__ Wh,
    const float* __restrict__ Wg1, const float* __restrict__ Wf1,
    const float* __restrict__ Wpre, const float* __restrict__ Winit,
    f16* __restrict__ WcatF, f16* __restrict__ WhtopF, f16* __restrict__ Wg1F,
    f16* __restrict__ Wf1F, f16* __restrict__ WpreF, f16* __restrict__ WinitF) {
    int t = blockIdx.x * 256 + threadIdx.x;
    int l = t & 63;
    int lr = l & 15, lh = l >> 4;
    if (t < 24 * 8 * 64) {
        int idx = t >> 6; int nt = idx >> 3, ks = idx & 7;
        int wv = nt / 6, ntl = nt % 6;
        int grp = ntl >> 1, pr = ntl & 1;
        int ncol = (2 * wv + pr) * 16 + lr;
        f16x8 v;
#pragma unroll
        for (int j = 0; j < 8; j++) {
            int k = ks * 32 + lh * 8 + j;
            float x;
            if (grp == 0)      x = Wz[k * 128 + ncol];
            else if (grp == 1) x = Wr[k * 128 + ncol];
            else               x = (k >= 128) ? Wh[k * 128 + ncol] : 0.0f;
            v[j] = (f16)x;
        }
        *(f16x8*)(WcatF + (size_t)t * 8) = v;
    } else if (t < 24 * 8 * 64 + 8 * 4 * 64) {
        int t2 = t - 24 * 8 * 64;
        int idx = t2 >> 6; int nt = idx >> 2, ks = idx & 3;
        int n = nt * 16 + lr;
        f16x8 v;
#pragma unroll
        for (int j = 0; j < 8; j++) {
            int k = ks * 32 + lh * 8 + j;
            v[j] = (f16)Wh[k * 128 + n];
        }
        *(f16x8*)(WhtopF + (size_t)t2 * 8) = v;
    } else if (t < 24 * 8 * 64 + 8 * 4 * 64 + 4 * 4 * 64) {
        int t3 = t - (24 * 8 * 64 + 8 * 4 * 64);
        int idx = t3 >> 6; int nt = idx >> 2, ks = idx & 3;
        int cg = nt * 16 + lr;
        f16x8 v;
#pragma unroll
        for (int j = 0; j < 8; j++) {
            int k = ks * 32 + lh * 8 + j;
            v[j] = (f16)((cg < 32) ? Wg1[k * GH + cg] : Wg1[(128 + k) * GH + (cg - 32)]);
        }
        *(f16x8*)(Wg1F + (size_t)t3 * 8) = v;
    } else if (t < 24 * 8 * 64 + 8 * 4 * 64 + 4 * 4 * 64 + 8 * 8 * 64) {
        int t4 = t - (24 * 8 * 64 + 8 * 4 * 64 + 4 * 4 * 64);
        int idx = t4 >> 6; int nt = idx >> 3, ks = idx & 7;
        int n = nt * 16 + lr;
        f16x8 v;
#pragma unroll
        for (int j = 0; j < 8; j++) {
            int k = ks * 32 + lh * 8 + j;
            v[j] = (f16)Wf1[k * 128 + n];
        }
        *(f16x8*)(Wf1F + (size_t)t4 * 8) = v;
    } else if (t < 19456 + 2 * 64) {
        int t5 = t - 19456;
        int nt = t5 >> 6;
        f16x8 v;
#pragma unroll
        for (int j = 0; j < 8; j++) {
            int k = lh * 8 + j;           // K padded 16->32
            v[j] = (k < FIN) ? (f16)Wpre[k * PRE + nt * 16 + lr] : (f16)0.0f;
        }
        *(f16x8*)(WpreF + (size_t)t5 * 8) = v;
    } else if (t < 19456 + 128 + 8 * 64) {
        int t6 = t - 19456 - 128;
        int nt = t6 >> 6;
        f16x8 v;
#pragma unroll
        for (int j = 0; j < 8; j++) {
            int k = lh * 8 + j;
            v[j] = (f16)Winit[k * C + nt * 16 + lr];
        }
        *(f16x8*)(WinitF + (size_t)t6 * 8) = v;
    }
}

// fused preproc + layer-0 gate, all MFMA. 32 nodes/block.
__global__ __launch_bounds__(256) void k_pre_gate(
    const float* __restrict__ x, const float* __restrict__ bpre, const float* __restrict__ binit,
    const float* __restrict__ dis,
    const f16* __restrict__ WpreF, const f16* __restrict__ WinitF,
    const f16* __restrict__ Wg1F, const float* __restrict__ bg1,
    f16* __restrict__ h0_16, f16* __restrict__ rec,
    float* __restrict__ A) {
    __shared__ f16 ps[32 * 32];     // pre, 64B-stride swizzled
    __shared__ f16 za[32 * 128];    // h, 256B-stride swizzled
    char* psB = (char*)ps;
    char* zaB = (char*)za;
    int tid = threadIdx.x;
    int l = tid & 63, w = tid >> 6;
    int lr = l & 15, lh = l >> 4;
    int n0 = blockIdx.x * 32;
    int rt0 = w >> 1, ct = w & 1;

    f16x8 xa = {};
    {
        int gn = n0 + rt0 * 16 + lr;
        if (gn < NODES && lh < 2) {
            float4 xv0 = *(const float4*)(x + (size_t)gn * FIN + lh * 8);
            float4 xv1 = *(const float4*)(x + (size_t)gn * FIN + lh * 8 + 4);
            xa[0] = (f16)xv0.x; xa[1] = (f16)xv0.y; xa[2] = (f16)xv0.z; xa[3] = (f16)xv0.w;
            xa[4] = (f16)xv1.x; xa[5] = (f16)xv1.y; xa[6] = (f16)xv1.z; xa[7] = (f16)xv1.w;
        }
    }
    f16x8 bA = *(const f16x8*)(WpreF + ((size_t)ct * 64 + l) * 8);
    f32x4 accA; accA[0] = accA[1] = accA[2] = accA[3] = 0.0f;
    accA = __builtin_amdgcn_mfma_f32_16x16x32_f16(xa, bA, accA, 0, 0, 0);
    {
        float bp = bpre[ct * 16 + lr];
#pragma unroll
        for (int j = 0; j < 4; j++) {
            int row = rt0 * 16 + lh * 4 + j;
            float v = fmaxf(accA[j] + bp, 0.0f);
            *(f16*)(psB + ps_off(row, (ct * 16 + lr) * 2)) = (f16)v;
        }
    }
    __syncthreads();

    f16x8 pa0 = *(const f16x8*)(psB + ps_off(lr, lh * 16));
    f16x8 pa1 = *(const f16x8*)(psB + ps_off(lr + 16, lh * 16));
    f32x4 accB[2][2];
#pragma unroll
    for (int rt = 0; rt < 2; rt++)
#pragma unroll
        for (int ntl = 0; ntl < 2; ntl++)
#pragma unroll
            for (int j = 0; j < 4; j++) accB[rt][ntl][j] = 0.0f;
#pragma unroll
    for (int ntl = 0; ntl < 2; ntl++) {
        f16x8 b = *(const f16x8*)(WinitF + ((size_t)((w * 2 + ntl) * 64 + l)) * 8);
        accB[0][ntl] = __builtin_amdgcn_mfma_f32_16x16x32_f16(pa0, b, accB[0][ntl], 0, 0, 0);
        accB[1][ntl] = __builtin_amdgcn_mfma_f32_16x16x32_f16(pa1, b, accB[1][ntl], 0, 0, 0);
    }
#pragma unroll
    for (int rt = 0; rt < 2; rt++)
#pragma unroll
        for (int ntl = 0; ntl < 2; ntl++) {
            int cg = (w * 2 + ntl) * 16 + lr;
            float bi = binit[cg];
#pragma unroll
            for (int j = 0; j < 4; j++) {
                int row = rt * 16 + lh * 4 + j;
                float v = fmaxf(accB[rt][ntl][j] + bi, 0.0f);
                *(f16*)(zaB + swz_off(row, cg * 2, 256)) = (f16)v;
            }
        }
    __syncthreads();

    for (int p = tid; p < 32 * 16; p += 256) {
        int row = p >> 4, seg = p & 15;
        int gn = n0 + row;
        if (gn < NODES) {
            f16x8 v = *(const f16x8*)(zaB + swz_off(row, seg * 16, 256));
            *(f16x8*)(h0_16 + (size_t)gn * C + seg * 8) = v;
            float dn = dis[gn];
            f16x8 od;
#pragma unroll
            for (int j = 0; j < 8; j++) od[j] = (f16)((float)v[j] * dn);
            *(f16x8*)(rec + (size_t)gn * RECS + 32 + seg * 8) = od;
        }
    }

    f32x4 acc3[2];
#pragma unroll
    for (int rt = 0; rt < 2; rt++)
#pragma unroll
        for (int j = 0; j < 4; j++) acc3[rt][j] = 0.0f;
#pragma unroll
    for (int ks = 0; ks < 4; ks++) {
        int kk = ks * 32 + lh * 8;
        f16x8 a0 = *(const f16x8*)(zaB + swz_off(lr,      kk * 2, 256));
        f16x8 a1 = *(const f16x8*)(zaB + swz_off(lr + 16, kk * 2, 256));
        f16x8 b = *(const f16x8*)(Wg1F + ((size_t)(w * 4 + ks) * 64 + l) * 8);
        acc3[0] = __builtin_amdgcn_mfma_f32_16x16x32_f16(a0, b, acc3[0], 0, 0, 0);
        acc3[1] = __builtin_amdgcn_mfma_f32_16x16x32_f16(a1, b, acc3[1], 0, 0, 0);
    }
    int col3 = w * 16 + lr;
#pragma unroll
    for (int rt = 0; rt < 2; rt++)
#pragma unroll
        for (int j = 0; j < 4; j++) {
            int row = rt * 16 + lh * 4 + j;
            int gn = n0 + row;
            if (gn < NODES) {
                float v = acc3[rt][j];
                if (col3 < 32) A[(size_t)gn * GH + bperm(col3)] = v + bg1[col3];
                else           rec[(size_t)gn * RECS + bperm(col3 - 32)] = (f16)v;
            }
        }
}

// FUSED layer: msg (gate+aggregate into LDS) + GRU update via MFMA.
// 32 nodes/block. Reads recC/A_cur (layer l state), writes recN/A_nxt.
__global__ __launch_bounds__(256) void k_layer(
    const int* __restrict__ start, const int2* __restrict__ esort,
    const float* __restrict__ dis, const float* __restrict__ rdis,
    const float* __restrict__ A_cur, const f16* __restrict__ recC,
    f16* __restrict__ recN, float* __restrict__ A_nxt,
    const f16* __restrict__ WcatF, const f16* __restrict__ WhtopF, const f16* __restrict__ Wg1F,
    const float* __restrict__ Wg1, const float* __restrict__ Wg2, const float* __restrict__ bg2,
    const float* __restrict__ bz, const float* __restrict__ br, const float* __restrict__ bh,
    const float* __restrict__ bg1) {
    __shared__ f16 za[32 * 256];    // swizzled, 512B stride: [h | aggr]; reused for h_new
    __shared__ f16 rhbuf[32 * 128]; // swizzled, 256B stride
    char* zaB = (char*)za;
    char* rhB = (char*)rhbuf;
    int tid = threadIdx.x;
    int l = tid & 63, w = tid >> 6;
    int lr = l & 15, lh = l >> 4;
    int n0 = blockIdx.x * 32;

    // phase 0: stage h (=hd*rdis) into za byte cols 0..255
    for (int p = tid; p < 32 * 16; p += 256) {
        int row = p >> 4, seg = p & 15;
        int gn = n0 + row;
        f16x8 v = {};
        if (gn < NODES) {
            v = *(const f16x8*)(recC + (size_t)gn * RECS + 32 + seg * 8);
            float rd = rdis[gn];
#pragma unroll
            for (int j = 0; j < 8; j++) v[j] = (f16)((float)v[j] * rd);
        }
        *(f16x8*)(zaB + swz_off(row, seg * 16, 512)) = v;
    }

    // phase 1: msg. Wave w handles rows w*8..w*8+7; 8 lanes/edge, 1-deep prefetch.
    // aggr channel c lives at byte col 256 + 2c (cols 128..255 of za).
    {
        int k8 = l & 7;
        int q = l >> 3;
        const float* wg1e = Wg1 + 2 * C * GH;
        float wea0 = wg1e[k8], wea1 = wg1e[k8 + 8], wea2 = wg1e[k8 + 16], wea3 = wg1e[k8 + 24];
        float w20 = Wg2[k8], w21 = Wg2[k8 + 8], w22 = Wg2[k8 + 16], w23 = Wg2[k8 + 24];
        float b2 = bg2[0];
        for (int i = 0; i < 8; i++) {
            int row = w * 8 + i;
            int gn = n0 + row;
            int s0 = 0, s1 = 0;
            float dci = 0.0f;
            float4 a4 = make_float4(0.0f, 0.0f, 0.0f, 0.0f);
            if (gn < NODES) {
                s0 = start[gn]; s1 = start[gn + 1];
                dci = dis[gn];
                a4 = *(const float4*)(A_cur + (size_t)gn * GH + k8 * 4);
            }
            float acc[16];
#pragma unroll
            for (int j = 0; j < 16; j++) acc[j] = 0.0f;
            int s = s0 + q;
            f16x8 ha0 = {}, hb0 = {};
            f16x4 bb0 = {};
            float ea0 = 0.0f;
            if (s < s1) {
                int2 e0 = esort[s];
                ea0 = __int_as_float(e0.y);
                const f16* rr = recC + (size_t)e0.x * RECS;
                bb0 = *(const f16x4*)(rr + k8 * 4);
                ha0 = *(const f16x8*)(rr + 32 + k8 * 16);
                hb0 = *(const f16x8*)(rr + 32 + k8 * 16 + 8);
            }
            while (s < s1) {
                int s2 = s + 8;
                f16x8 ha1 = {}, hb1 = {};
                f16x4 bb1 = {};
                float ea1 = 0.0f;
                if (s2 < s1) {
                    int2 e1 = esort[s2];
                    ea1 = __int_as_float(e1.y);
                    const f16* rr = recC + (size_t)e1.x * RECS;
                    bb1 = *(const f16x4*)(rr + k8 * 4);
                    ha1 = *(const f16x8*)(rr + 32 + k8 * 16);
                    hb1 = *(const f16x8*)(rr + 32 + k8 * 16 + 8);
                }
                float t0 = fmaxf(a4.x + (float)bb0[0] + ea0 * wea0, 0.0f);
                float t1 = fmaxf(a4.y + (float)bb0[1] + ea0 * wea1, 0.0f);
                float t2 = fmaxf(a4.z + (float)bb0[2] + ea0 * wea2, 0.0f);
                float t3 = fmaxf(a4.w + (float)bb0[3] + ea0 * wea3, 0.0f);
                float p = t0 * w20;
                p = fmaf(t1, w21, p);
                p = fmaf(t2, w22, p);
                p = fmaf(t3, w23, p);
                p += __shfl_xor(p, 4, 8);
                p += __shfl_xor(p, 2, 8);
                p += __shfl_xor(p, 1, 8);
                float coef = sigmoidf_(p + b2);
#pragma unroll
                for (int j = 0; j < 8; j++) {
                    acc[j]     = fmaf(coef, (float)ha0[j], acc[j]);
                    acc[8 + j] = fmaf(coef, (float)hb0[j], acc[8 + j]);
                }
                ha0 = ha1; hb0 = hb1; bb0 = bb1; ea0 = ea1;
                s = s2;
            }
#pragma unroll
            for (int j = 0; j < 16; j++) {
                acc[j] += __shfl_xor(acc[j], 8, 64);
                acc[j] += __shfl_xor(acc[j], 16, 64);
                acc[j] += __shfl_xor(acc[j], 32, 64);
            }
            if (l < 8) {   // aggr channels k8*16..+15 -> byte cols 256 + k8*32 .. +31
                f16x8 o1, o2;
#pragma unroll
                for (int j = 0; j < 8; j++) {
                    o1[j] = (f16)(acc[j] * dci);
                    o2[j] = (f16)(acc[8 + j] * dci);
                }
                *(f16x8*)(zaB + swz_off(row, 256 + k8 * 32, 512)) = o1;
                *(f16x8*)(zaB + swz_off(row, 256 + k8 * 32 + 16, 512)) = o2;
            }
        }
    }
    __syncthreads();

    // phase 2: GEMM1 tiles [z0,z1,r0,r1,p0,p1] per wave
    f32x4 acc[2][6];
#pragma unroll
    for (int rt = 0; rt < 2; rt++)
#pragma unroll
        for (int n = 0; n < 6; n++)
#pragma unroll
            for (int j = 0; j < 4; j++) acc[rt][n][j] = 0.0f;
#pragma unroll
    for (int ks = 0; ks < 8; ks++) {
        int kk = ks * 32 + lh * 8;
        f16x8 a0 = *(const f16x8*)(zaB + swz_off(lr,      kk * 2, 512));
        f16x8 a1 = *(const f16x8*)(zaB + swz_off(lr + 16, kk * 2, 512));
#pragma unroll
        for (int ntl = 0; ntl < 6; ntl++) {
            f16x8 b = *(const f16x8*)(WcatF + ((size_t)((w * 6 + ntl) * 8 + ks) * 64 + l) * 8);
            acc[0][ntl] = __builtin_amdgcn_mfma_f32_16x16x32_f16(a0, b, acc[0][ntl], 0, 0, 0);
            acc[1][ntl] = __builtin_amdgcn_mfma_f32_16x16x32_f16(a1, b, acc[1][ntl], 0, 0, 0);
        }
    }

    // epilogue1: z->reg (sigmoid), r*h -> rhbuf (h from za), p stays in acc[rt][4/5]
    float zreg[2][2][4];
#pragma unroll
    for (int rt = 0; rt < 2; rt++)
#pragma unroll
        for (int pr = 0; pr < 2; pr++) {
            int cg = (2 * w + pr) * 16 + lr;
#pragma unroll
            for (int j = 0; j < 4; j++) {
                int row = rt * 16 + lh * 4 + j;
                zreg[rt][pr][j] = sigmoidf_(acc[rt][pr][j] + bz[cg]);
                float rv = sigmoidf_(acc[rt][2 + pr][j] + br[cg]);
                float hv = (float)*(const f16*)(zaB + swz_off(row, cg * 2, 512));
                *(f16*)(rhB + swz_off(row, cg * 2, 256)) = (f16)(rv * hv);
            }
        }
    __syncthreads();

    // GEMM2: hc_pre = p + bh + (r*h) @ Wh_top
    f32x4 acc2[2][2];
#pragma unroll
    for (int rt = 0; rt < 2; rt++)
#pragma unroll
        for (int pr = 0; pr < 2; pr++) {
            int cg = (2 * w + pr) * 16 + lr;
#pragma unroll
            for (int j = 0; j < 4; j++)
                acc2[rt][pr][j] = acc[rt][4 + pr][j] + bh[cg];
        }
#pragma unroll
    for (int ks = 0; ks < 4; ks++) {
        int kk = ks * 32 + lh * 8;
        f16x8 a0 = *(const f16x8*)(rhB + swz_off(lr,      kk * 2, 256));
        f16x8 a1 = *(const f16x8*)(rhB + swz_off(lr + 16, kk * 2, 256));
#pragma unroll
        for (int pr = 0; pr < 2; pr++) {
            f16x8 b = *(const f16x8*)(WhtopF + ((size_t)((w * 2 + pr) * 4 + ks) * 64 + l) * 8);
            acc2[0][pr] = __builtin_amdgcn_mfma_f32_16x16x32_f16(a0, b, acc2[0][pr], 0, 0, 0);
            acc2[1][pr] = __builtin_amdgcn_mfma_f32_16x16x32_f16(a1, b, acc2[1][pr], 0, 0, 0);
        }
    }

    // epilogue2: h_new = (1-z)*hold(za) + z*relu(hc); write recN hd16; stage h_new into za
#pragma unroll
    for (int rt = 0; rt < 2; rt++)
#pragma unroll
        for (int pr = 0; pr < 2; pr++) {
            int cg = (2 * w + pr) * 16 + lr;
#pragma unroll
            for (int j = 0; j < 4; j++) {
                int row = rt * 16 + lh * 4 + j;
                int gn = n0 + row;
                float hc = fmaxf(acc2[rt][pr][j], 0.0f);
                float z = zreg[rt][pr][j];
                float hold = (float)*(const f16*)(zaB + swz_off(row, cg * 2, 512));
                float hn = (1.0f - z) * hold + z * hc;
                if (gn < NODES) {
                    recN[(size_t)gn * RECS + 32 + cg] = (f16)(hn * dis[gn]);
                }
                *(f16*)(zaB + swz_off(row, cg * 2, 512)) = (f16)hn;
            }
        }
    __syncthreads();

    // GEMM3: A|B16 = h_new @ Wg1F (both outputs permuted)
    f32x4 acc3[2];
#pragma unroll
    for (int rt = 0; rt < 2; rt++)
#pragma unroll
        for (int j = 0; j < 4; j++) acc3[rt][j] = 0.0f;
#pragma unroll
    for (int ks = 0; ks < 4; ks++) {
        int kk = ks * 32 + lh * 8;
        f16x8 a0 = *(const f16x8*)(zaB + swz_off(lr,      kk * 2, 512));
        f16x8 a1 = *(const f16x8*)(zaB + swz_off(lr + 16, kk * 2, 512));
        f16x8 b = *(const f16x8*)(Wg1F + ((size_t)(w * 4 + ks) * 64 + l) * 8);
        acc3[0] = __builtin_amdgcn_mfma_f32_16x16x32_f16(a0, b, acc3[0], 0, 0, 0);
        acc3[1] = __builtin_amdgcn_mfma_f32_16x16x32_f16(a1, b, acc3[1], 0, 0, 0);
    }
    int col3 = w * 16 + lr;
#pragma unroll
    for (int rt = 0; rt < 2; rt++)
#pragma unroll
        for (int j = 0; j < 4; j++) {
            int row = rt * 16 + lh * 4 + j;
            int gn = n0 + row;
            if (gn < NODES) {
                float v = acc3[rt][j];
                if (col3 < 32) A_nxt[(size_t)gn * GH + bperm(col3)] = v + bg1[col3];
                else           recN[(size_t)gn * RECS + bperm(col3 - 32)] = (f16)v;
            }
        }
}

// final head via MFMA: f = relu([h0_16 | h(=hd*rdis)]@Wf1+bf1); out = f@Wf2+bf2
__global__ __launch_bounds__(256) void k_final_mfma(
    const f16* __restrict__ h0_16, const f16* __restrict__ rec, const float* __restrict__ rdis,
    const f16* __restrict__ Wf1F, const float* __restrict__ bf1,
    const float* __restrict__ Wf2, const float* __restrict__ bf2,
    float* __restrict__ out) {
    __shared__ float fs[32][132];   // aliased during stage/GEMM as f16 za [32][256] swizzled
    char* zaB = (char*)&fs[0][0];
    int tid = threadIdx.x;
    int l = tid & 63, w = tid >> 6;
    int lr = l & 15, lh = l >> 4;
    int n0 = blockIdx.x * 32;

    for (int p = tid; p < 32 * 16; p += 256) {
        int row = p >> 4, seg = p & 15;
        int gn = n0 + row;
        f16x8 v = {};
        if (gn < NODES) v = *(const f16x8*)(h0_16 + (size_t)gn * C + seg * 8);
        *(f16x8*)(zaB + swz_off(row, seg * 16, 512)) = v;
    }
    for (int p = tid; p < 32 * 16; p += 256) {
        int row = p >> 4, seg = p & 15;
        int gn = n0 + row;
        f16x8 v = {};
        if (gn < NODES) {
            v = *(const f16x8*)(rec + (size_t)gn * RECS + 32 + seg * 8);
            float rd = rdis[gn];
#pragma unroll
            for (int j = 0; j < 8; j++) v[j] = (f16)((float)v[j] * rd);
        }
        *(f16x8*)(zaB + swz_off(row, 256 + seg * 16, 512)) = v;
    }
    __syncthreads();

    f32x4 acc[2][2];
#pragma unroll
    for (int rt = 0; rt < 2; rt++)
#pragma unroll
        for (int n = 0; n < 2; n++)
#pragma unroll
            for (int j = 0; j < 4; j++) acc[rt][n][j] = 0.0f;
#pragma unroll
    for (int ks = 0; ks < 8; ks++) {
        int kk = ks * 32 + lh * 8;
        f16x8 a0 = *(const f16x8*)(zaB + swz_off(lr,      kk * 2, 512));
        f16x8 a1 = *(const f16x8*)(zaB + swz_off(lr + 16, kk * 2, 512));
#pragma unroll
        for (int ntl = 0; ntl < 2; ntl++) {
            f16x8 b = *(const f16x8*)(Wf1F + ((size_t)((w * 2 + ntl) * 8 + ks) * 64 + l) * 8);
            acc[0][ntl] = __builtin_amdgcn_mfma_f32_16x16x32_f16(a0, b, acc[0][ntl], 0, 0, 0);
            acc[1][ntl] = __builtin_amdgcn_mfma_f32_16x16x32_f16(a1, b, acc[1][ntl], 0, 0, 0);
        }
    }
    __syncthreads();  // za reads done before fs overwrite

#pragma unroll
    for (int rt = 0; rt < 2; rt++)
#pragma unroll
        for (int ntl = 0; ntl < 2; ntl++) {
            int cg = (w * 2 + ntl) * 16 + lr;
#pragma unroll
            for (int j = 0; j < 4; j++) {
                int row = rt * 16 + lh * 4 + j;
                fs[row][cg] = fmaxf(acc[rt][ntl][j] + bf1[cg], 0.0f);
            }
        }
    __syncthreads();

    if (tid < 64) {
        int n = tid >> 1, o = tid & 1;
        int gn = n0 + n;
        if (gn < NODES) {
            float a = bf2[o];
#pragma unroll 16
            for (int c = 0; c < C; c++) a = fmaf(fs[n][c], Wf2[c * 2 + o], a);
            out[(size_t)gn * 2 + o] = a;
        }
    }
}

extern "C" void kernel_launch(void* const* d_in, const int* in_sizes, int n_in,
                              void* d_out, int out_size, void* d_ws, size_t ws_size,
                              hipStream_t stream) {
    const float* x    = (const float*)d_in[0];
    const int*   eidx = (const int*)d_in[1];
    const float* eattr= (const float*)d_in[2];
    const float* Wpre = (const float*)d_in[3];  const float* bpre = (const float*)d_in[4];
    const float* Winit= (const float*)d_in[5];  const float* binit= (const float*)d_in[6];
    const float* Wg1  = (const float*)d_in[7];  const float* bg1  = (const float*)d_in[8];
    const float* Wg2  = (const float*)d_in[9];  const float* bg2  = (const float*)d_in[10];
    const float* Wz   = (const float*)d_in[11]; const float* bz   = (const float*)d_in[12];
    const float* Wr   = (const float*)d_in[13]; const float* br   = (const float*)d_in[14];
    const float* Wh   = (const float*)d_in[15]; const float* bh   = (const float*)d_in[16];
    const float* Wf1  = (const float*)d_in[17]; const float* bf1  = (const float*)d_in[18];
    const float* Wf2  = (const float*)d_in[19]; const float* bf2  = (const float*)d_in[20];
    float* out = (float*)d_out;

    float* ws  = (float*)d_ws;
    float* dis = ws;                               // N (deg during preamble, then rsqrt)
    float* rdis= dis + NODES;                      // N (sqrt(deg+1))
    float* A0  = rdis + NODES;                     // N*GH f32 (permuted)
    float* A1  = A0 + (size_t)NODES * GH;          // N*GH f32 (permuted)
    int*   start = (int*)(A1 + (size_t)NODES * GH);    // N+1
    int*   bsum  = start + NODES + 1;                  // SCB
    int*   bscan = bsum + SCB;                         // SCB
    int*   bcnt  = bscan + SCB;                        // NB*16 (64B-padded counters)
    int2*  bbuf  = (int2*)(((size_t)(bcnt + NB * 16) + 7) & ~(size_t)7);  // NB*BCAP int2
    int2*  esort = bbuf + (size_t)NB * BCAP;           // ETOT int2
    size_t f16_base = (size_t)((int*)(esort + ETOT) - (int*)ws);
    f16_base = (f16_base + 3) & ~(size_t)3;            // 16B align
    f16* h0_16  = (f16*)(ws + f16_base);               // N*C f16
    f16* rec0   = h0_16 + (size_t)NODES * C;           // N*RECS f16
    f16* rec1   = rec0 + (size_t)NODES * RECS;         // N*RECS f16
    f16* WcatF  = rec1 + (size_t)NODES * RECS;         // 24*8*64*8 f16
    f16* WhtopF = WcatF + 24 * 8 * 64 * 8;
    f16* Wg1F   = WhtopF + 8 * 4 * 64 * 8;
    f16* Wf1F   = Wg1F + 4 * 4 * 64 * 8;
    f16* WpreF  = Wf1F + 8 * 8 * 64 * 8;               // 2*64*8 f16
    f16* WinitF = WpreF + 2 * 64 * 8;                  // 8*64*8 f16
    size_t f16_total = (size_t)NODES * (C + 2 * RECS)
                     + (24 * 8 + 8 * 4 + 4 * 4 + 8 * 8 + 2 + 8) * 64 * 8;
    const size_t REQ = (f16_base + (f16_total + 1) / 2) * sizeof(float);
    if (ws_size < REQ) return;

    hipMemsetAsync(dis, 0, NODES * sizeof(float), stream);
    hipMemsetAsync(bcnt, 0, NB * 16 * sizeof(int), stream);
    k_degree<<<(NEDGES + 255) / 256, 256, 0, stream>>>(eidx + NEDGES, dis);
    k_scan1<<<SCB, SCT, 0, stream>>>(dis, bsum);
    k_scan2<<<1, 64, 0, stream>>>(bsum, bscan, start);
    k_scan3<<<SCB, SCT, 0, stream>>>(dis, rdis, bscan, start);   // writes dis + rdis
    k_bucket2<<<BIN_BLOCKS, 256, 0, stream>>>(eidx, eattr, bcnt, bbuf);
    k_csr2<<<NB, 256, 0, stream>>>(bcnt, bbuf, start, esort);
    k_prep_w<<<(19456 + 128 + 512 + 255) / 256, 256, 0, stream>>>(
        Wz, Wr, Wh, Wg1, Wf1, Wpre, Winit, WcatF, WhtopF, Wg1F, Wf1F, WpreF, WinitF);
    k_pre_gate<<<(NODES + 31) / 32, 256, 0, stream>>>(
        x, bpre, binit, dis, WpreF, WinitF, Wg1F, bg1, h0_16, rec0, A0);

    for (int l = 0; l < LAYERS; l++) {
        f16* recC = (l & 1) ? rec1 : rec0;
        f16* recN = (l & 1) ? rec0 : rec1;
        float* Ac = (l & 1) ? A1 : A0;
        float* An = (l & 1) ? A0 : A1;
        k_layer<<<(NODES + 31) / 32, 256, 0, stream>>>(
            start, esort, dis, rdis, Ac, recC, recN, An,
            WcatF, WhtopF, Wg1F, Wg1, Wg2, bg2, bz, br, bh, bg1);
    }
    k_final_mfma<<<(NODES + 31) / 32, 256, 0, stream>>>(
        h0_16, rec1, rdis, Wf1F, bf1, Wf2, bf2, out);
}

// Round 20
// 557.212 us; speedup vs baseline: 1.4196x; 1.4196x over previous
//
#include <hip/hip_runtime.h>
#include <math.h>

#define NODES 50000
#define NEDGES 800000
#define ETOT (NEDGES + NODES)
#define FIN 16
#define PRE 32
#define C 128
#define GH 32
#define LAYERS 5
#define RECS 160   // f16 per node record: [B16perm:32 | hd16:128] where hd = dis[n]*h[n]
#define SCB 64     // scan blocks
#define SCT 256    // scan threads/block
#define SCCH ((NODES + SCB*SCT - 1) / (SCB*SCT))   // elems per thread (=4)
#define NB ((NODES + 255) >> 8)   // 196 coarse buckets (256 nodes each)
#define BCAP 6144                 // max real edges per bucket (mean 4096, +32 sigma)
#define LOUTC (BCAP + 256)        // LDS staging capacity (edges + self loops)
#define BIN_BLOCKS 98
#define EPB ((NEDGES + BIN_BLOCKS - 1) / BIN_BLOCKS)

typedef _Float16 f16;
typedef f16 f16x8 __attribute__((ext_vector_type(8)));
typedef f16 f16x4 __attribute__((ext_vector_type(4)));
typedef f16 f16x2 __attribute__((ext_vector_type(2)));
typedef float f32x4 __attribute__((ext_vector_type(4)));

__device__ __forceinline__ float sigmoidf_(float x) { return 1.0f / (1.0f + __expf(-x)); }

// XOR-swizzled LDS byte offset: 16B-block index ^= (row&7)  (stride >= 128B)
__device__ __forceinline__ int swz_off(int row, int bytecol, int stride) {
    return row * stride + ((((bytecol) >> 4) ^ (row & 7)) << 4) + (bytecol & 15);
}
// 64B-stride variant: block index ^= (row&3)
__device__ __forceinline__ int ps_off(int row, int bytecol) {
    return row * 64 + ((((bytecol) >> 4) ^ (row & 3)) << 4) + (bytecol & 15);
}

// gate channel c (0..31) -> permuted position, so msg lane k8 reads one vector
__device__ __forceinline__ int bperm(int c) { return 4 * (c & 7) + (c >> 3); }

__global__ void k_degree(const int* __restrict__ col, float* __restrict__ deg) {
    int e = blockIdx.x * blockDim.x + threadIdx.x;
    if (e < NEDGES) atomicAdd(&deg[col[e]], 1.0f);
}

// parallel scan, stage 1: per-block sums of (deg+1)
__global__ __launch_bounds__(SCT) void k_scan1(const float* __restrict__ deg, int* __restrict__ bsum) {
    __shared__ int ws4[SCT / 64];
    int b = blockIdx.x, t = threadIdx.x;
    int lane = t & 63, wv = t >> 6;
    int base = (b * SCT + t) * SCCH;
    int sum = 0;
#pragma unroll
    for (int j = 0; j < SCCH; j++) {
        int i = base + j;
        if (i < NODES) sum += (int)deg[i] + 1;
    }
#pragma unroll
    for (int off = 32; off > 0; off >>= 1) sum += __shfl_xor(sum, off, 64);
    if (lane == 0) ws4[wv] = sum;
    __syncthreads();
    if (t == 0) {
        int tot = 0;
#pragma unroll
        for (int j = 0; j < SCT / 64; j++) tot += ws4[j];
        bsum[b] = tot;
    }
}

// stage 2: exclusive scan of SCB block sums (single wave)
__global__ __launch_bounds__(64) void k_scan2(const int* __restrict__ bsum, int* __restrict__ bscan,
                                              int* __restrict__ start) {
    int t = threadIdx.x;
    int v = (t < SCB) ? bsum[t] : 0;
    int x = v;
#pragma unroll
    for (int off = 1; off < 64; off <<= 1) {
        int tt = __shfl_up(x, off, 64);
        if (t >= off) x += tt;
    }
    if (t < SCB) bscan[t] = x - v;
    if (t == SCB - 1) start[NODES] = x;
}

// stage 3: per-element exclusive prefix -> start; dis=rsqrt(deg+1), rdis=sqrt(deg+1)
__global__ __launch_bounds__(SCT) void k_scan3(
    float* __restrict__ deg_dis, float* __restrict__ rdis, const int* __restrict__ bscan,
    int* __restrict__ start) {
    __shared__ int woff[SCT / 64];
    int b = blockIdx.x, t = threadIdx.x;
    int lane = t & 63, wv = t >> 6;
    int base = (b * SCT + t) * SCCH;
    int v[SCCH]; int sum = 0;
#pragma unroll
    for (int j = 0; j < SCCH; j++) {
        int i = base + j;
        v[j] = (i < NODES) ? (int)deg_dis[i] + 1 : 0;
        sum += v[j];
    }
    int x = sum;
#pragma unroll
    for (int off = 1; off < 64; off <<= 1) {
        int tt = __shfl_up(x, off, 64);
        if (lane >= off) x += tt;
    }
    int texcl = x - sum;
    if (lane == 63) woff[wv] = x;
    __syncthreads();
    int wbase = 0;
    for (int j = 0; j < wv; j++) wbase += woff[j];
    int run = bscan[b] + wbase + texcl;
#pragma unroll
    for (int j = 0; j < SCCH; j++) {
        int i = base + j;
        if (i < NODES) {
            start[i] = run;
            float fv = (float)v[j];
            deg_dis[i] = rsqrtf(fv);
            rdis[i] = sqrtf(fv);
        }
        run += v[j];
    }
}

// CSR phase 1: hierarchical binning. Per block: LDS count -> one global reservation
// per bucket (padded counters) -> scatter into reserved contiguous chunk.
__global__ __launch_bounds__(256) void k_bucket2(
    const int* __restrict__ eidx, const float* __restrict__ eattr,
    int* __restrict__ bcnt /* NB, stride 16 ints */, int2* __restrict__ bbuf) {
    __shared__ int cnt[NB];
    __shared__ int gbase[NB];
    __shared__ int cur[NB];
    int b = blockIdx.x, t = threadIdx.x;
    int e0 = b * EPB;
    int e1 = e0 + EPB; if (e1 > NEDGES) e1 = NEDGES;
    for (int i = t; i < NB; i += 256) cnt[i] = 0;
    __syncthreads();
    for (int e = e0 + t; e < e1; e += 256) {
        int ci = eidx[NEDGES + e];
        atomicAdd(&cnt[ci >> 8], 1);
    }
    __syncthreads();
    for (int i = t; i < NB; i += 256) {
        gbase[i] = (cnt[i] > 0) ? atomicAdd(&bcnt[i * 16], cnt[i]) : 0;
        cur[i] = 0;
    }
    __syncthreads();
    for (int e = e0 + t; e < e1; e += 256) {
        int r = eidx[e], ci = eidx[NEDGES + e];
        float ea = eattr[e];
        int bk = ci >> 8;
        int pos = gbase[bk] + atomicAdd(&cur[bk], 1);
        if (pos < BCAP)
            bbuf[(size_t)bk * BCAP + pos] =
                make_int2((r & 0xFFFF) | ((ci & 255) << 16), __float_as_int(ea));
    }
}

// CSR phase 2: block per bucket; LDS-staged per-node grouping, dense contiguous flush
__global__ __launch_bounds__(256) void k_csr2(
    const int* __restrict__ bcnt, const int2* __restrict__ bbuf,
    const int* __restrict__ start, int2* __restrict__ esort) {
    __shared__ int2 lout[LOUTC];
    __shared__ int lcur[256];
    int b = blockIdx.x, t = threadIdx.x;
    int lo = b << 8;
    int hi = lo + 256; if (hi > NODES) hi = NODES;
    int nn = hi - lo;
    int sbase = start[lo];
    int total = start[hi] - sbase;
    if (t < nn) lcur[t] = start[lo + t] - sbase;
    __syncthreads();
    int n = bcnt[b * 16]; if (n > BCAP) n = BCAP;
    for (int i = t; i < n; i += 256) {
        int2 w = bbuf[(size_t)b * BCAP + i];
        int cil = (w.x >> 16) & 255;
        int r = w.x & 0xFFFF;
        int pos = atomicAdd(&lcur[cil], 1);
        if (pos < LOUTC) lout[pos] = make_int2(r, w.y);
    }
    if (t < nn) {   // self loop for each node
        int pos = atomicAdd(&lcur[t], 1);
        if (pos < LOUTC) lout[pos] = make_int2(lo + t, 0);
    }
    __syncthreads();
    int lim = total < LOUTC ? total : LOUTC;
    for (int i = t; i < lim; i += 256) esort[sbase + i] = lout[i];
}

// fragment-ordered f16 weight buffers.
__global__ __launch_bounds__(256) void k_prep_w(
    const float* __restrict__ Wz, const float* __restrict__ Wr, const float* __restrict__ Wh,
    const float* __restrict__ Wg1, const float* __restrict__ Wf1,
    const float* __restrict__ Wpre, const float* __restrict__ Winit,
    f16* __restrict__ WcatF, f16* __restrict__ WhtopF, f16* __restrict__ Wg1F,
    f16* __restrict__ Wf1F, f16* __restrict__ WpreF, f16* __restrict__ WinitF) {
    int t = blockIdx.x * 256 + threadIdx.x;
    int l = t & 63;
    int lr = l & 15, lh = l >> 4;
    if (t < 24 * 8 * 64) {
        int idx = t >> 6; int nt = idx >> 3, ks = idx & 7;
        int wv = nt / 6, ntl = nt % 6;
        int grp = ntl >> 1, pr = ntl & 1;
        int ncol = (2 * wv + pr) * 16 + lr;
        f16x8 v;
#pragma unroll
        for (int j = 0; j < 8; j++) {
            int k = ks * 32 + lh * 8 + j;
            float x;
            if (grp == 0)      x = Wz[k * 128 + ncol];
            else if (grp == 1) x = Wr[k * 128 + ncol];
            else               x = (k >= 128) ? Wh[k * 128 + ncol] : 0.0f;
            v[j] = (f16)x;
        }
        *(f16x8*)(WcatF + (size_t)t * 8) = v;
    } else if (t < 24 * 8 * 64 + 8 * 4 * 64) {
        int t2 = t - 24 * 8 * 64;
        int idx = t2 >> 6; int nt = idx >> 2, ks = idx & 3;
        int n = nt * 16 + lr;
        f16x8 v;
#pragma unroll
        for (int j = 0; j < 8; j++) {
            int k = ks * 32 + lh * 8 + j;
            v[j] = (f16)Wh[k * 128 + n];
        }
        *(f16x8*)(WhtopF + (size_t)t2 * 8) = v;
    } else if (t < 24 * 8 * 64 + 8 * 4 * 64 + 4 * 4 * 64) {
        int t3 = t - (24 * 8 * 64 + 8 * 4 * 64);
        int idx = t3 >> 6; int nt = idx >> 2, ks = idx & 3;
        int cg = nt * 16 + lr;
        f16x8 v;
#pragma unroll
        for (int j = 0; j < 8; j++) {
            int k = ks * 32 + lh * 8 + j;
            v[j] = (f16)((cg < 32) ? Wg1[k * GH + cg] : Wg1[(128 + k) * GH + (cg - 32)]);
        }
        *(f16x8*)(Wg1F + (size_t)t3 * 8) = v;
    } else if (t < 24 * 8 * 64 + 8 * 4 * 64 + 4 * 4 * 64 + 8 * 8 * 64) {
        int t4 = t - (24 * 8 * 64 + 8 * 4 * 64 + 4 * 4 * 64);
        int idx = t4 >> 6; int nt = idx >> 3, ks = idx & 7;
        int n = nt * 16 + lr;
        f16x8 v;
#pragma unroll
        for (int j = 0; j < 8; j++) {
            int k = ks * 32 + lh * 8 + j;
            v[j] = (f16)Wf1[k * 128 + n];
        }
        *(f16x8*)(Wf1F + (size_t)t4 * 8) = v;
    } else if (t < 19456 + 2 * 64) {
        int t5 = t - 19456;
        int nt = t5 >> 6;
        f16x8 v;
#pragma unroll
        for (int j = 0; j < 8; j++) {
            int k = lh * 8 + j;           // K padded 16->32
            v[j] = (k < FIN) ? (f16)Wpre[k * PRE + nt * 16 + lr] : (f16)0.0f;
        }
        *(f16x8*)(WpreF + (size_t)t5 * 8) = v;
    } else if (t < 19456 + 128 + 8 * 64) {
        int t6 = t - 19456 - 128;
        int nt = t6 >> 6;
        f16x8 v;
#pragma unroll
        for (int j = 0; j < 8; j++) {
            int k = lh * 8 + j;
            v[j] = (f16)Winit[k * C + nt * 16 + lr];
        }
        *(f16x8*)(WinitF + (size_t)t6 * 8) = v;
    }
}

// fused preproc + layer-0 gate, all MFMA. 32 nodes/block.
__global__ __launch_bounds__(256) void k_pre_gate(
    const float* __restrict__ x, const float* __restrict__ bpre, const float* __restrict__ binit,
    const float* __restrict__ dis,
    const f16* __restrict__ WpreF, const f16* __restrict__ WinitF,
    const f16* __restrict__ Wg1F, const float* __restrict__ bg1,
    f16* __restrict__ h0_16, f16* __restrict__ rec,
    float* __restrict__ A) {
    __shared__ f16 ps[32 * 32];     // pre, 64B-stride swizzled
    __shared__ f16 za[32 * 128];    // h, 256B-stride swizzled
    char* psB = (char*)ps;
    char* zaB = (char*)za;
    int tid = threadIdx.x;
    int l = tid & 63, w = tid >> 6;
    int lr = l & 15, lh = l >> 4;
    int n0 = blockIdx.x * 32;
    int rt0 = w >> 1, ct = w & 1;

    f16x8 xa = {};
    {
        int gn = n0 + rt0 * 16 + lr;
        if (gn < NODES && lh < 2) {
            float4 xv0 = *(const float4*)(x + (size_t)gn * FIN + lh * 8);
            float4 xv1 = *(const float4*)(x + (size_t)gn * FIN + lh * 8 + 4);
            xa[0] = (f16)xv0.x; xa[1] = (f16)xv0.y; xa[2] = (f16)xv0.z; xa[3] = (f16)xv0.w;
            xa[4] = (f16)xv1.x; xa[5] = (f16)xv1.y; xa[6] = (f16)xv1.z; xa[7] = (f16)xv1.w;
        }
    }
    f16x8 bA = *(const f16x8*)(WpreF + ((size_t)ct * 64 + l) * 8);
    f32x4 accA; accA[0] = accA[1] = accA[2] = accA[3] = 0.0f;
    accA = __builtin_amdgcn_mfma_f32_16x16x32_f16(xa, bA, accA, 0, 0, 0);
    {
        float bp = bpre[ct * 16 + lr];
#pragma unroll
        for (int j = 0; j < 4; j++) {
            int row = rt0 * 16 + lh * 4 + j;
            float v = fmaxf(accA[j] + bp, 0.0f);
            *(f16*)(psB + ps_off(row, (ct * 16 + lr) * 2)) = (f16)v;
        }
    }
    __syncthreads();

    f16x8 pa0 = *(const f16x8*)(psB + ps_off(lr, lh * 16));
    f16x8 pa1 = *(const f16x8*)(psB + ps_off(lr + 16, lh * 16));
    f32x4 accB[2][2];
#pragma unroll
    for (int rt = 0; rt < 2; rt++)
#pragma unroll
        for (int ntl = 0; ntl < 2; ntl++)
#pragma unroll
            for (int j = 0; j < 4; j++) accB[rt][ntl][j] = 0.0f;
#pragma unroll
    for (int ntl = 0; ntl < 2; ntl++) {
        f16x8 b = *(const f16x8*)(WinitF + ((size_t)((w * 2 + ntl) * 64 + l)) * 8);
        accB[0][ntl] = __builtin_amdgcn_mfma_f32_16x16x32_f16(pa0, b, accB[0][ntl], 0, 0, 0);
        accB[1][ntl] = __builtin_amdgcn_mfma_f32_16x16x32_f16(pa1, b, accB[1][ntl], 0, 0, 0);
    }
#pragma unroll
    for (int rt = 0; rt < 2; rt++)
#pragma unroll
        for (int ntl = 0; ntl < 2; ntl++) {
            int cg = (w * 2 + ntl) * 16 + lr;
            float bi = binit[cg];
#pragma unroll
            for (int j = 0; j < 4; j++) {
                int row = rt * 16 + lh * 4 + j;
                float v = fmaxf(accB[rt][ntl][j] + bi, 0.0f);
                *(f16*)(zaB + swz_off(row, cg * 2, 256)) = (f16)v;
            }
        }
    __syncthreads();

    for (int p = tid; p < 32 * 16; p += 256) {
        int row = p >> 4, seg = p & 15;
        int gn = n0 + row;
        if (gn < NODES) {
            f16x8 v = *(const f16x8*)(zaB + swz_off(row, seg * 16, 256));
            *(f16x8*)(h0_16 + (size_t)gn * C + seg * 8) = v;
            float dn = dis[gn];
            f16x8 od;
#pragma unroll
            for (int j = 0; j < 8; j++) od[j] = (f16)((float)v[j] * dn);
            *(f16x8*)(rec + (size_t)gn * RECS + 32 + seg * 8) = od;
        }
    }

    f32x4 acc3[2];
#pragma unroll
    for (int rt = 0; rt < 2; rt++)
#pragma unroll
        for (int j = 0; j < 4; j++) acc3[rt][j] = 0.0f;
#pragma unroll
    for (int ks = 0; ks < 4; ks++) {
        int kk = ks * 32 + lh * 8;
        f16x8 a0 = *(const f16x8*)(zaB + swz_off(lr,      kk * 2, 256));
        f16x8 a1 = *(const f16x8*)(zaB + swz_off(lr + 16, kk * 2, 256));
        f16x8 b = *(const f16x8*)(Wg1F + ((size_t)(w * 4 + ks) * 64 + l) * 8);
        acc3[0] = __builtin_amdgcn_mfma_f32_16x16x32_f16(a0, b, acc3[0], 0, 0, 0);
        acc3[1] = __builtin_amdgcn_mfma_f32_16x16x32_f16(a1, b, acc3[1], 0, 0, 0);
    }
    int col3 = w * 16 + lr;
#pragma unroll
    for (int rt = 0; rt < 2; rt++)
#pragma unroll
        for (int j = 0; j < 4; j++) {
            int row = rt * 16 + lh * 4 + j;
            int gn = n0 + row;
            if (gn < NODES) {
                float v = acc3[rt][j];
                if (col3 < 32) A[(size_t)gn * GH + bperm(col3)] = v + bg1[col3];
                else           rec[(size_t)gn * RECS + bperm(col3 - 32)] = (f16)v;
            }
        }
}

// fused gate+aggregate: wave per node, EIGHTH-WAVE (8 lanes) per edge, 1-deep prefetch.
__global__ __launch_bounds__(256) void k_msg(
    const int* __restrict__ start, const int2* __restrict__ esort,
    const float* __restrict__ dis,
    const float* __restrict__ A, const f16* __restrict__ rec,
    const float* __restrict__ Wg1, const float* __restrict__ Wg2, const float* __restrict__ bg2,
    f16* __restrict__ aggr16) {
    int wid = (blockIdx.x * blockDim.x + threadIdx.x) >> 6;
    int lane = threadIdx.x & 63;
    if (wid >= NODES) return;
    int k8 = lane & 7;
    int q = lane >> 3;
    int s0 = start[wid], s1 = start[wid + 1];
    float4 a4 = *(const float4*)(A + (size_t)wid * GH + k8 * 4);   // channels {k8,k8+8,k8+16,k8+24}
    const float* wg1e = Wg1 + 2 * C * GH;
    float wea0 = wg1e[k8], wea1 = wg1e[k8 + 8], wea2 = wg1e[k8 + 16], wea3 = wg1e[k8 + 24];
    float w20 = Wg2[k8], w21 = Wg2[k8 + 8], w22 = Wg2[k8 + 16], w23 = Wg2[k8 + 24];
    float b2 = bg2[0];
    float dci = dis[wid];
    float acc[16];
#pragma unroll
    for (int j = 0; j < 16; j++) acc[j] = 0.0f;

    int s = s0 + q;
    f16x8 ha0 = {}, hb0 = {};
    f16x4 bb0 = {};
    float ea0 = 0.0f;
    if (s < s1) {
        int2 e0 = esort[s];
        ea0 = __int_as_float(e0.y);
        const f16* rr = rec + (size_t)e0.x * RECS;
        bb0 = *(const f16x4*)(rr + k8 * 4);
        ha0 = *(const f16x8*)(rr + 32 + k8 * 16);
        hb0 = *(const f16x8*)(rr + 32 + k8 * 16 + 8);
    }
    while (s < s1) {
        int s2 = s + 8;
        f16x8 ha1 = {}, hb1 = {};
        f16x4 bb1 = {};
        float ea1 = 0.0f;
        if (s2 < s1) {                       // prefetch next edge's record
            int2 e1 = esort[s2];
            ea1 = __int_as_float(e1.y);
            const f16* rr = rec + (size_t)e1.x * RECS;
            bb1 = *(const f16x4*)(rr + k8 * 4);
            ha1 = *(const f16x8*)(rr + 32 + k8 * 16);
            hb1 = *(const f16x8*)(rr + 32 + k8 * 16 + 8);
        }
        float t0 = fmaxf(a4.x + (float)bb0[0] + ea0 * wea0, 0.0f);
        float t1 = fmaxf(a4.y + (float)bb0[1] + ea0 * wea1, 0.0f);
        float t2 = fmaxf(a4.z + (float)bb0[2] + ea0 * wea2, 0.0f);
        float t3 = fmaxf(a4.w + (float)bb0[3] + ea0 * wea3, 0.0f);
        float p = t0 * w20;
        p = fmaf(t1, w21, p);
        p = fmaf(t2, w22, p);
        p = fmaf(t3, w23, p);
        p += __shfl_xor(p, 4, 8);
        p += __shfl_xor(p, 2, 8);
        p += __shfl_xor(p, 1, 8);
        float coef = sigmoidf_(p + b2);
#pragma unroll
        for (int j = 0; j < 8; j++) {
            acc[j]     = fmaf(coef, (float)ha0[j], acc[j]);
            acc[8 + j] = fmaf(coef, (float)hb0[j], acc[8 + j]);
        }
        ha0 = ha1; hb0 = hb1; bb0 = bb1; ea0 = ea1;
        s = s2;
    }
#pragma unroll
    for (int j = 0; j < 16; j++) {
        acc[j] += __shfl_xor(acc[j], 8, 64);
        acc[j] += __shfl_xor(acc[j], 16, 64);
        acc[j] += __shfl_xor(acc[j], 32, 64);
    }
    if (lane < 8) {
        f16x8 o1, o2;
#pragma unroll
        for (int j = 0; j < 8; j++) { o1[j] = (f16)(acc[j] * dci); o2[j] = (f16)(acc[8 + j] * dci); }
        *(f16x8*)(aggr16 + (size_t)wid * C + k8 * 16) = o1;
        *(f16x8*)(aggr16 + (size_t)wid * C + k8 * 16 + 8) = o2;
    }
}

// GRU update via MFMA; per-wave column-tile ownership keeps z,p in registers.
__global__ __launch_bounds__(256) void k_update_mfma(
    f16* __restrict__ rec, const f16* __restrict__ aggr16,
    const float* __restrict__ dis, const float* __restrict__ rdis,
    const f16* __restrict__ WcatF, const f16* __restrict__ WhtopF, const f16* __restrict__ Wg1F,
    const float* __restrict__ bz, const float* __restrict__ br, const float* __restrict__ bh,
    const float* __restrict__ bg1,
    float* __restrict__ A) {
    __shared__ f16 za[32 * 256];    // swizzled, row stride 512B; reused for h_new staging
    __shared__ f16 rhbuf[32 * 128]; // swizzled, row stride 256B
    char* zaB = (char*)za;
    char* rhB = (char*)rhbuf;
    int tid = threadIdx.x;
    int l = tid & 63, w = tid >> 6;
    int lr = l & 15, lh = l >> 4;
    int n0 = blockIdx.x * 32;

    // stage za = [h (=hd*rdis) | aggr16]
    for (int p = tid; p < 32 * 16; p += 256) {
        int row = p >> 4, seg = p & 15;
        int gn = n0 + row;
        f16x8 v = {};
        if (gn < NODES) {
            v = *(const f16x8*)(rec + (size_t)gn * RECS + 32 + seg * 8);
            float rd = rdis[gn];
#pragma unroll
            for (int j = 0; j < 8; j++) v[j] = (f16)((float)v[j] * rd);
        }
        *(f16x8*)(zaB + swz_off(row, seg * 16, 512)) = v;
    }
    for (int p = tid; p < 32 * 16; p += 256) {
        int row = p >> 4, seg = p & 15;
        int gn = n0 + row;
        f16x8 v = {};
        if (gn < NODES) v = *(const f16x8*)(aggr16 + (size_t)gn * C + seg * 8);
        *(f16x8*)(zaB + swz_off(row, 256 + seg * 16, 512)) = v;
    }
    __syncthreads();

    // GEMM1: tiles [z0,z1,r0,r1,p0,p1] per wave
    f32x4 acc[2][6];
#pragma unroll
    for (int rt = 0; rt < 2; rt++)
#pragma unroll
        for (int n = 0; n < 6; n++)
#pragma unroll
            for (int j = 0; j < 4; j++) acc[rt][n][j] = 0.0f;
#pragma unroll
    for (int ks = 0; ks < 8; ks++) {
        int kk = ks * 32 + lh * 8;
        f16x8 a0 = *(const f16x8*)(zaB + swz_off(lr,      kk * 2, 512));
        f16x8 a1 = *(const f16x8*)(zaB + swz_off(lr + 16, kk * 2, 512));
#pragma unroll
        for (int ntl = 0; ntl < 6; ntl++) {
            f16x8 b = *(const f16x8*)(WcatF + ((size_t)((w * 6 + ntl) * 8 + ks) * 64 + l) * 8);
            acc[0][ntl] = __builtin_amdgcn_mfma_f32_16x16x32_f16(a0, b, acc[0][ntl], 0, 0, 0);
            acc[1][ntl] = __builtin_amdgcn_mfma_f32_16x16x32_f16(a1, b, acc[1][ntl], 0, 0, 0);
        }
    }

    // epilogue1: z->reg (sigmoid), r*h -> rhbuf (h from za), p stays in acc[rt][4/5]
    float zreg[2][2][4];
#pragma unroll
    for (int rt = 0; rt < 2; rt++)
#pragma unroll
        for (int pr = 0; pr < 2; pr++) {
            int cg = (2 * w + pr) * 16 + lr;
#pragma unroll
            for (int j = 0; j < 4; j++) {
                int row = rt * 16 + lh * 4 + j;
                zreg[rt][pr][j] = sigmoidf_(acc[rt][pr][j] + bz[cg]);
                float rv = sigmoidf_(acc[rt][2 + pr][j] + br[cg]);
                float hv = (float)*(const f16*)(zaB + swz_off(row, cg * 2, 512));
                *(f16*)(rhB + swz_off(row, cg * 2, 256)) = (f16)(rv * hv);
            }
        }
    __syncthreads();

    // GEMM2: hc_pre = p + bh + (r*h) @ Wh_top
    f32x4 acc2[2][2];
#pragma unroll
    for (int rt = 0; rt < 2; rt++)
#pragma unroll
        for (int pr = 0; pr < 2; pr++) {
            int cg = (2 * w + pr) * 16 + lr;
#pragma unroll
            for (int j = 0; j < 4; j++)
                acc2[rt][pr][j] = acc[rt][4 + pr][j] + bh[cg];
        }
#pragma unroll
    for (int ks = 0; ks < 4; ks++) {
        int kk = ks * 32 + lh * 8;
        f16x8 a0 = *(const f16x8*)(rhB + swz_off(lr,      kk * 2, 256));
        f16x8 a1 = *(const f16x8*)(rhB + swz_off(lr + 16, kk * 2, 256));
#pragma unroll
        for (int pr = 0; pr < 2; pr++) {
            f16x8 b = *(const f16x8*)(WhtopF + ((size_t)((w * 2 + pr) * 4 + ks) * 64 + l) * 8);
            acc2[0][pr] = __builtin_amdgcn_mfma_f32_16x16x32_f16(a0, b, acc2[0][pr], 0, 0, 0);
            acc2[1][pr] = __builtin_amdgcn_mfma_f32_16x16x32_f16(a1, b, acc2[1][pr], 0, 0, 0);
        }
    }

    // epilogue2: h_new = (1-z)*hold(za) + z*relu(hc); write rec hd16; stage h_new into za
#pragma unroll
    for (int rt = 0; rt < 2; rt++)
#pragma unroll
        for (int pr = 0; pr < 2; pr++) {
            int cg = (2 * w + pr) * 16 + lr;
#pragma unroll
            for (int j = 0; j < 4; j++) {
                int row = rt * 16 + lh * 4 + j;
                int gn = n0 + row;
                float hc = fmaxf(acc2[rt][pr][j], 0.0f);
                float z = zreg[rt][pr][j];
                float hold = (float)*(const f16*)(zaB + swz_off(row, cg * 2, 512));
                float hn = (1.0f - z) * hold + z * hc;
                if (gn < NODES) {
                    rec[(size_t)gn * RECS + 32 + cg] = (f16)(hn * dis[gn]);
                }
                *(f16*)(zaB + swz_off(row, cg * 2, 512)) = (f16)hn;
            }
        }
    __syncthreads();

    // GEMM3: A|B16 = h_new @ Wg1F (both outputs permuted)
    f32x4 acc3[2];
#pragma unroll
    for (int rt = 0; rt < 2; rt++)
#pragma unroll
        for (int j = 0; j < 4; j++) acc3[rt][j] = 0.0f;
#pragma unroll
    for (int ks = 0; ks < 4; ks++) {
        int kk = ks * 32 + lh * 8;
        f16x8 a0 = *(const f16x8*)(zaB + swz_off(lr,      kk * 2, 512));
        f16x8 a1 = *(const f16x8*)(zaB + swz_off(lr + 16, kk * 2, 512));
        f16x8 b = *(const f16x8*)(Wg1F + ((size_t)(w * 4 + ks) * 64 + l) * 8);
        acc3[0] = __builtin_amdgcn_mfma_f32_16x16x32_f16(a0, b, acc3[0], 0, 0, 0);
        acc3[1] = __builtin_amdgcn_mfma_f32_16x16x32_f16(a1, b, acc3[1], 0, 0, 0);
    }
    int col3 = w * 16 + lr;
#pragma unroll
    for (int rt = 0; rt < 2; rt++)
#pragma unroll
        for (int j = 0; j < 4; j++) {
            int row = rt * 16 + lh * 4 + j;
            int gn = n0 + row;
            if (gn < NODES) {
                float v = acc3[rt][j];
                if (col3 < 32) A[(size_t)gn * GH + bperm(col3)] = v + bg1[col3];
                else           rec[(size_t)gn * RECS + bperm(col3 - 32)] = (f16)v;
            }
        }
}

// final head via MFMA: f = relu([h0_16 | h(=hd*rdis)]@Wf1+bf1); out = f@Wf2+bf2
__global__ __launch_bounds__(256) void k_final_mfma(
    const f16* __restrict__ h0_16, const f16* __restrict__ rec, const float* __restrict__ rdis,
    const f16* __restrict__ Wf1F, const float* __restrict__ bf1,
    const float* __restrict__ Wf2, const float* __restrict__ bf2,
    float* __restrict__ out) {
    __shared__ float fs[32][132];   // aliased during stage/GEMM as f16 za [32][256] swizzled
    char* zaB = (char*)&fs[0][0];
    int tid = threadIdx.x;
    int l = tid & 63, w = tid >> 6;
    int lr = l & 15, lh = l >> 4;
    int n0 = blockIdx.x * 32;

    for (int p = tid; p < 32 * 16; p += 256) {
        int row = p >> 4, seg = p & 15;
        int gn = n0 + row;
        f16x8 v = {};
        if (gn < NODES) v = *(const f16x8*)(h0_16 + (size_t)gn * C + seg * 8);
        *(f16x8*)(zaB + swz_off(row, seg * 16, 512)) = v;
    }
    for (int p = tid; p < 32 * 16; p += 256) {
        int row = p >> 4, seg = p & 15;
        int gn = n0 + row;
        f16x8 v = {};
        if (gn < NODES) {
            v = *(const f16x8*)(rec + (size_t)gn * RECS + 32 + seg * 8);
            float rd = rdis[gn];
#pragma unroll
            for (int j = 0; j < 8; j++) v[j] = (f16)((float)v[j] * rd);
        }
        *(f16x8*)(zaB + swz_off(row, 256 + seg * 16, 512)) = v;
    }
    __syncthreads();

    f32x4 acc[2][2];
#pragma unroll
    for (int rt = 0; rt < 2; rt++)
#pragma unroll
        for (int n = 0; n < 2; n++)
#pragma unroll
            for (int j = 0; j < 4; j++) acc[rt][n][j] = 0.0f;
#pragma unroll
    for (int ks = 0; ks < 8; ks++) {
        int kk = ks * 32 + lh * 8;
        f16x8 a0 = *(const f16x8*)(zaB + swz_off(lr,      kk * 2, 512));
        f16x8 a1 = *(const f16x8*)(zaB + swz_off(lr + 16, kk * 2, 512));
#pragma unroll
        for (int ntl = 0; ntl < 2; ntl++) {
            f16x8 b = *(const f16x8*)(Wf1F + ((size_t)((w * 2 + ntl) * 8 + ks) * 64 + l) * 8);
            acc[0][ntl] = __builtin_amdgcn_mfma_f32_16x16x32_f16(a0, b, acc[0][ntl], 0, 0, 0);
            acc[1][ntl] = __builtin_amdgcn_mfma_f32_16x16x32_f16(a1, b, acc[1][ntl], 0, 0, 0);
        }
    }
    __syncthreads();  // za reads done before fs overwrite

#pragma unroll
    for (int rt = 0; rt < 2; rt++)
#pragma unroll
        for (int ntl = 0; ntl < 2; ntl++) {
            int cg = (w * 2 + ntl) * 16 + lr;
#pragma unroll
            for (int j = 0; j < 4; j++) {
                int row = rt * 16 + lh * 4 + j;
                fs[row][cg] = fmaxf(acc[rt][ntl][j] + bf1[cg], 0.0f);
            }
        }
    __syncthreads();

    if (tid < 64) {
        int n = tid >> 1, o = tid & 1;
        int gn = n0 + n;
        if (gn < NODES) {
            float a = bf2[o];
#pragma unroll 16
            for (int c = 0; c < C; c++) a = fmaf(fs[n][c], Wf2[c * 2 + o], a);
            out[(size_t)gn * 2 + o] = a;
        }
    }
}

extern "C" void kernel_launch(void* const* d_in, const int* in_sizes, int n_in,
                              void* d_out, int out_size, void* d_ws, size_t ws_size,
                              hipStream_t stream) {
    const float* x    = (const float*)d_in[0];
    const int*   eidx = (const int*)d_in[1];
    const float* eattr= (const float*)d_in[2];
    const float* Wpre = (const float*)d_in[3];  const float* bpre = (const float*)d_in[4];
    const float* Winit= (const float*)d_in[5];  const float* binit= (const float*)d_in[6];
    const float* Wg1  = (const float*)d_in[7];  const float* bg1  = (const float*)d_in[8];
    const float* Wg2  = (const float*)d_in[9];  const float* bg2  = (const float*)d_in[10];
    const float* Wz   = (const float*)d_in[11]; const float* bz   = (const float*)d_in[12];
    const float* Wr   = (const float*)d_in[13]; const float* br   = (const float*)d_in[14];
    const float* Wh   = (const float*)d_in[15]; const float* bh   = (const float*)d_in[16];
    const float* Wf1  = (const float*)d_in[17]; const float* bf1  = (const float*)d_in[18];
    const float* Wf2  = (const float*)d_in[19]; const float* bf2  = (const float*)d_in[20];
    float* out = (float*)d_out;

    float* ws  = (float*)d_ws;
    float* dis = ws;                               // N (deg during preamble, then rsqrt)
    float* rdis= dis + NODES;                      // N (sqrt(deg+1))
    float* A   = rdis + NODES;                     // N*GH f32 (permuted)
    int*   start = (int*)(A + (size_t)NODES * GH);     // N+1
    int*   bsum  = start + NODES + 1;                  // SCB
    int*   bscan = bsum + SCB;                         // SCB
    int*   bcnt  = bscan + SCB;                        // NB*16 (64B-padded counters)
    int2*  bbuf  = (int2*)(((size_t)(bcnt + NB * 16) + 7) & ~(size_t)7);  // NB*BCAP int2
    int2*  esort = bbuf + (size_t)NB * BCAP;           // ETOT int2
    size_t f16_base = (size_t)((int*)(esort + ETOT) - (int*)ws);
    f16_base = (f16_base + 3) & ~(size_t)3;            // 16B align
    f16* h0_16  = (f16*)(ws + f16_base);               // N*C f16
    f16* rec    = h0_16 + (size_t)NODES * C;           // N*RECS f16
    f16* aggr16 = rec + (size_t)NODES * RECS;          // N*C f16
    f16* WcatF  = aggr16 + (size_t)NODES * C;          // 24*8*64*8 f16
    f16* WhtopF = WcatF + 24 * 8 * 64 * 8;
    f16* Wg1F   = WhtopF + 8 * 4 * 64 * 8;
    f16* Wf1F   = Wg1F + 4 * 4 * 64 * 8;
    f16* WpreF  = Wf1F + 8 * 8 * 64 * 8;               // 2*64*8 f16
    f16* WinitF = WpreF + 2 * 64 * 8;                  // 8*64*8 f16
    size_t f16_total = (size_t)NODES * (C + RECS + C)
                     + (24 * 8 + 8 * 4 + 4 * 4 + 8 * 8 + 2 + 8) * 64 * 8;
    const size_t REQ = (f16_base + (f16_total + 1) / 2) * sizeof(float);
    if (ws_size < REQ) return;

    hipMemsetAsync(dis, 0, NODES * sizeof(float), stream);
    hipMemsetAsync(bcnt, 0, NB * 16 * sizeof(int), stream);
    k_degree<<<(NEDGES + 255) / 256, 256, 0, stream>>>(eidx + NEDGES, dis);
    k_scan1<<<SCB, SCT, 0, stream>>>(dis, bsum);
    k_scan2<<<1, 64, 0, stream>>>(bsum, bscan, start);
    k_scan3<<<SCB, SCT, 0, stream>>>(dis, rdis, bscan, start);   // writes dis + rdis
    k_bucket2<<<BIN_BLOCKS, 256, 0, stream>>>(eidx, eattr, bcnt, bbuf);
    k_csr2<<<NB, 256, 0, stream>>>(bcnt, bbuf, start, esort);
    k_prep_w<<<(19456 + 128 + 512 + 255) / 256, 256, 0, stream>>>(
        Wz, Wr, Wh, Wg1, Wf1, Wpre, Winit, WcatF, WhtopF, Wg1F, Wf1F, WpreF, WinitF);
    k_pre_gate<<<(NODES + 31) / 32, 256, 0, stream>>>(
        x, bpre, binit, dis, WpreF, WinitF, Wg1F, bg1, h0_16, rec, A);

    for (int l = 0; l < LAYERS; l++) {
        k_msg<<<(NODES * 64 + 255) / 256, 256, 0, stream>>>(
            start, esort, dis, A, rec, Wg1, Wg2, bg2, aggr16);
        k_update_mfma<<<(NODES + 31) / 32, 256, 0, stream>>>(
            rec, aggr16, dis, rdis, WcatF, WhtopF, Wg1F, bz, br, bh, bg1, A);
    }
    k_final_mfma<<<(NODES + 31) / 32, 256, 0, stream>>>(h0_16, rec, rdis, Wf1F, bf1, Wf2, bf2, out);
}